// Round 4
// baseline (145.275 us; speedup 1.0000x reference)
//
#include <hip/hip_runtime.h>

// out[token, h] = W[h, ids[token]] + b[h]   (one-hot matmul == column gather)
// W: [HIDDEN, VOCAB] row-major f32.
//
// Round-3 ladder: unsorted gather 170us (FETCH 504MB) -> id-sorted 62.6us.
// Round-4 changes:
//  1. Sort fused into ONE single-block kernel (LDS hist + Blelloch scan +
//     scatter) -- removes 3 dispatches + global round-trips from the chain.
//  2. Gather: 8 sorted tokens/block, each thread covers its 4-h slice for
//     all 8 tokens; loads ordered row-major so same-row loads (ids within
//     ~31 -> 2-3 cache lines) L1-hit back-to-back. 32 loads in flight.

#define VOCAB  32000
#define HIDDEN 1024
#define TPB    8      // tokens per gather block
#define NBINS  2048   // bins of 16 ids (one 64B line per h-row); 2000 < 2048

// Single-block counting sort by line-bin (id>>4). perm[rank] = orig token.
__global__ __launch_bounds__(1024) void sort_kernel(
    const int* __restrict__ ids, int n, int* __restrict__ perm)
{
    __shared__ int bins[NBINS];   // hist -> exclusive prefix -> running pos
    const int t = threadIdx.x;

    for (int i = t; i < NBINS; i += 1024) bins[i] = 0;
    __syncthreads();

    for (int i = t; i < n; i += 1024) atomicAdd(&bins[ids[i] >> 4], 1);
    __syncthreads();

    // In-LDS Blelloch exclusive scan over NBINS elements (1024 threads).
    int offset = 1;
    for (int d = NBINS >> 1; d > 0; d >>= 1) {
        if (t < d) {
            int ai = offset * (2 * t + 1) - 1;
            int bi = offset * (2 * t + 2) - 1;
            bins[bi] += bins[ai];
        }
        offset <<= 1;
        __syncthreads();
    }
    if (t == 0) bins[NBINS - 1] = 0;
    __syncthreads();
    for (int d = 1; d < NBINS; d <<= 1) {
        offset >>= 1;
        if (t < d) {
            int ai = offset * (2 * t + 1) - 1;
            int bi = offset * (2 * t + 2) - 1;
            int x = bins[ai];
            bins[ai] = bins[bi];
            bins[bi] += x;
        }
        __syncthreads();
    }

    for (int i = t; i < n; i += 1024) {
        int p = atomicAdd(&bins[ids[i] >> 4], 1);
        perm[p] = i;
    }
}

__global__ __launch_bounds__(256) void onehot_gather_kernel(
    const int* __restrict__ ids,
    const int* __restrict__ perm,   // may be nullptr (unsorted fallback)
    const float* __restrict__ W,
    const float* __restrict__ b,
    float* __restrict__ out,
    int n_tokens)
{
    // XCD-chunked swizzle: each XCD gets a contiguous (id-sorted) range.
    int bid = blockIdx.x;
    const int nwg = gridDim.x;
    if ((nwg & 7) == 0) bid = (bid & 7) * (nwg >> 3) + (bid >> 3);

    const int t    = threadIdx.x;
    const int wv   = t >> 6;              // wave 0..3 -> h range [256*wv, ...)
    const int lane = t & 63;
    const int h0   = wv * 256 + lane * 4; // 4 consecutive h per thread

    const int base = bid * TPB;

    // Per-block token set (uniform across threads; small L1-hot loads).
    int token[TPB];
    const float* Wcol[TPB];
    #pragma unroll
    for (int tk = 0; tk < TPB; ++tk) {
        int g = base + tk;
        int tok = (g < n_tokens) ? (perm ? perm[g] : g) : -1;
        token[tk] = tok;
        Wcol[tk]  = (tok >= 0) ? (W + (size_t)ids[tok]) : W;
    }

    // Phase 1: issue all gathers, row-major (row outer, token inner) so
    // same-row loads for nearby sorted ids L1-hit back-to-back.
    float v[TPB][4];
    #pragma unroll
    for (int k = 0; k < 4; ++k) {
        const size_t roff = (size_t)(h0 + k) * VOCAB;
        #pragma unroll
        for (int tk = 0; tk < TPB; ++tk)
            v[tk][k] = Wcol[tk][roff];
    }

    // Phase 2: bias + coalesced float4 stores to the ORIGINAL rows.
    const float4 bv = *reinterpret_cast<const float4*>(&b[h0]);
    #pragma unroll
    for (int tk = 0; tk < TPB; ++tk) {
        if (token[tk] < 0) continue;
        float4 o;
        o.x = v[tk][0] + bv.x;
        o.y = v[tk][1] + bv.y;
        o.z = v[tk][2] + bv.z;
        o.w = v[tk][3] + bv.w;
        *reinterpret_cast<float4*>(&out[(size_t)token[tk] * HIDDEN + h0]) = o;
    }
}

extern "C" void kernel_launch(void* const* d_in, const int* in_sizes, int n_in,
                              void* d_out, int out_size, void* d_ws, size_t ws_size,
                              hipStream_t stream)
{
    const int*   ids = (const int*)d_in[0];    // [BATCH*SEQ] int32
    const float* W   = (const float*)d_in[1];  // [HIDDEN, VOCAB] f32
    const float* b   = (const float*)d_in[2];  // [HIDDEN] f32
    float*       out = (float*)d_out;          // [BATCH*SEQ, HIDDEN] f32

    const int n_tokens = in_sizes[0];          // 8192
    const int nblocks  = (n_tokens + TPB - 1) / TPB;

    int* perm = nullptr;
    if (ws_size >= (size_t)n_tokens * sizeof(int)) {
        perm = (int*)d_ws;
        sort_kernel<<<dim3(1), dim3(1024), 0, stream>>>(ids, n_tokens, perm);
    }

    onehot_gather_kernel<<<dim3(nblocks), dim3(256), 0, stream>>>(
        ids, perm, W, b, out, n_tokens);
}

// Round 5
// 46.280 us; speedup vs baseline: 3.1390x; 3.1390x over previous
//
#include <hip/hip_runtime.h>

// out[token, h] = W[h, ids[token]] + b[h]   (one-hot matmul == column gather)
// W: [HIDDEN, VOCAB] row-major f32.
//
// Round-4 lesson: per-thread multi-token gather = scatter reads, ceiling
// ~3.2 TB/s effective (random 64B lines). Round-5: INVERT the loop.
// Tokens are counting-sorted into 500 bins of 64 vocab columns. Each block
// owns (bin, h-chunk): streams W[h0:h0+128, c0:c0+64) COALESCED into LDS,
// then writes lds[row][id-c0]+b[row] for each token in the bin (coalesced
// stores). Every W line belongs to exactly one bin -> W read exactly once,
// fully coalesced. Traffic floor: 131 MB read + 33 MB write ~= 26 us.

#define VOCAB   32000
#define HIDDEN  1024
#define CBIN    64     // vocab columns per bin
#define NBIN    500    // 32000 / 64
#define NBIN_P2 512
#define ROWS    128    // h rows per gather block
#define STRIDE  66     // LDS row stride (floats): 8B-aligned, mild bank spread
#define TCHUNK  128    // token metadata chunk per block pass

// ---- single-block counting sort by 64-wide bin (id>>6) ----
__global__ __launch_bounds__(1024) void sort_kernel(
    const int* __restrict__ ids, int n,
    int* __restrict__ perm, int* __restrict__ sorted_ids,
    int* __restrict__ bin_start)
{
    __shared__ int bins[NBIN_P2];
    const int t = threadIdx.x;

    for (int i = t; i < NBIN_P2; i += 1024) bins[i] = 0;
    __syncthreads();

    for (int i = t; i < n; i += 1024) atomicAdd(&bins[ids[i] >> 6], 1);
    __syncthreads();

    // Blelloch exclusive scan over NBIN_P2 = 512.
    int offset = 1;
    for (int d = NBIN_P2 >> 1; d > 0; d >>= 1) {
        if (t < d) {
            int ai = offset * (2 * t + 1) - 1;
            int bi = offset * (2 * t + 2) - 1;
            bins[bi] += bins[ai];
        }
        offset <<= 1;
        __syncthreads();
    }
    if (t == 0) bins[NBIN_P2 - 1] = 0;
    __syncthreads();
    for (int d = 1; d < NBIN_P2; d <<= 1) {
        offset >>= 1;
        if (t < d) {
            int ai = offset * (2 * t + 1) - 1;
            int bi = offset * (2 * t + 2) - 1;
            int x = bins[ai];
            bins[ai] = bins[bi];
            bins[bi] += x;
        }
        __syncthreads();
    }

    // Publish exclusive prefix as bin_start (before scatter mutates bins).
    for (int i = t; i < NBIN_P2; i += 1024) bin_start[i] = bins[i];
    if (t == 0) bin_start[NBIN_P2] = n;
    __syncthreads();

    for (int i = t; i < n; i += 1024) {
        int id = ids[i];
        int p = atomicAdd(&bins[id >> 6], 1);
        perm[p] = i;
        sorted_ids[p] = id;
    }
}

// ---- streaming gather: block = (bin, h-chunk) ----
__global__ __launch_bounds__(256) void stream_kernel(
    const float* __restrict__ W,
    const float* __restrict__ b,
    const int* __restrict__ perm,
    const int* __restrict__ sorted_ids,
    const int* __restrict__ bin_start,
    float* __restrict__ out)
{
    const int bin   = blockIdx.x;   // 0..NBIN-1
    const int chunk = blockIdx.y;   // 0..HIDDEN/ROWS-1
    const int n0 = bin_start[bin];
    const int n1 = bin_start[bin + 1];
    if (n0 == n1) return;           // uniform: no barriers crossed

    const int c0 = bin * CBIN;
    const int h0 = chunk * ROWS;
    const int t  = threadIdx.x;

    __shared__ float tile[ROWS * STRIDE];
    __shared__ int   tok_s[TCHUNK];
    __shared__ int   del_s[TCHUNK];

    // Stage W[h0:h0+ROWS, c0:c0+CBIN) -> LDS, coalesced float4 loads.
    {
        const int c4 = (t & 15) * 4;
        const int r0 = t >> 4;               // 16 rows per pass
        #pragma unroll
        for (int i = 0; i < ROWS / 16; ++i) {
            const int r = r0 + 16 * i;
            float4 v = *reinterpret_cast<const float4*>(
                &W[(size_t)(h0 + r) * VOCAB + c0 + c4]);
            float* dst = &tile[r * STRIDE + c4];   // 8B-aligned (stride even)
            *reinterpret_cast<float2*>(dst)     = make_float2(v.x, v.y);
            *reinterpret_cast<float2*>(dst + 2) = make_float2(v.z, v.w);
        }
    }

    const int   row  = t & (ROWS - 1);
    const float bias = b[h0 + row];
    const int   half = t >> 7;   // threads 0-127: even tokens; 128-255: odd

    for (int base = n0; base < n1; base += TCHUNK) {
        const int cnt = min(n1 - base, TCHUNK);
        if (t < cnt) {
            tok_s[t] = perm[base + t];
            del_s[t] = sorted_ids[base + t] - c0;
        }
        __syncthreads();   // tile + metadata ready

        for (int j = half; j < cnt; j += 2) {
            const int tok = tok_s[j];
            const float val = tile[row * STRIDE + del_s[j]] + bias;
            out[(size_t)tok * HIDDEN + h0 + row] = val;
        }
        __syncthreads();   // tok_s reused next pass
    }
}

// ---- fallback (no workspace): round-3 proven gather ----
__global__ __launch_bounds__(256) void fallback_kernel(
    const int* __restrict__ ids, const float* __restrict__ W,
    const float* __restrict__ b, float* __restrict__ out, int n_tokens)
{
    const int t = threadIdx.x;
    const int sub = t >> 6, lane = t & 63;
    const int token = blockIdx.x * 4 + sub;
    if (token >= n_tokens) return;
    const int id = ids[token];
    const float* Wcol = W + (size_t)id;
    float v[16];
    #pragma unroll
    for (int j = 0; j < 4; ++j) {
        const int h0 = j * 256 + lane * 4;
        #pragma unroll
        for (int k = 0; k < 4; ++k)
            v[j * 4 + k] = Wcol[(size_t)(h0 + k) * VOCAB];
    }
    float* orow = out + (size_t)token * HIDDEN;
    #pragma unroll
    for (int j = 0; j < 4; ++j) {
        const int h0 = j * 256 + lane * 4;
        const float4 bv = *reinterpret_cast<const float4*>(&b[h0]);
        float4 o;
        o.x = v[j*4+0] + bv.x; o.y = v[j*4+1] + bv.y;
        o.z = v[j*4+2] + bv.z; o.w = v[j*4+3] + bv.w;
        *reinterpret_cast<float4*>(&orow[h0]) = o;
    }
}

extern "C" void kernel_launch(void* const* d_in, const int* in_sizes, int n_in,
                              void* d_out, int out_size, void* d_ws, size_t ws_size,
                              hipStream_t stream)
{
    const int*   ids = (const int*)d_in[0];    // [BATCH*SEQ] int32
    const float* W   = (const float*)d_in[1];  // [HIDDEN, VOCAB] f32
    const float* b   = (const float*)d_in[2];  // [HIDDEN] f32
    float*       out = (float*)d_out;          // [BATCH*SEQ, HIDDEN] f32

    const int n_tokens = in_sizes[0];          // 8192

    // ws: perm[n] | sorted_ids[n] | bin_start[NBIN_P2+1]
    const size_t need = (size_t)(2 * n_tokens + NBIN_P2 + 1) * sizeof(int);
    if (ws_size >= need) {
        int* perm       = (int*)d_ws;
        int* sorted_ids = perm + n_tokens;
        int* bin_start  = sorted_ids + n_tokens;

        sort_kernel<<<dim3(1), dim3(1024), 0, stream>>>(
            ids, n_tokens, perm, sorted_ids, bin_start);

        stream_kernel<<<dim3(NBIN, HIDDEN / ROWS), dim3(256), 0, stream>>>(
            W, b, perm, sorted_ids, bin_start, out);
    } else {
        fallback_kernel<<<dim3((n_tokens + 3) / 4), dim3(256), 0, stream>>>(
            ids, W, b, out, n_tokens);
    }
}

// Round 6
// 44.048 us; speedup vs baseline: 3.2981x; 1.0507x over previous
//
#include <hip/hip_runtime.h>

// out[token, h] = W[h, ids[token]] + b[h]   (one-hot matmul == column gather)
// W: [HIDDEN, VOCAB] row-major f32.
//
// Ladder: unsorted gather 170us (FETCH 504MB, random-64B-line ceiling
// ~3.2TB/s) -> sorted gather 62.6us -> sort + inverted streaming 46.3us.
// Round-6: eliminate the serial single-block sort. ids are only 32KB
// (L2-resident broadcast), so each (bin, h-chunk) block filters the full
// id list itself. ONE kernel, no workspace, no dependency chain:
//   1. stage W[h0:h0+128, c0:c0+64) coalesced float4 -> LDS, TRANSPOSED
//      [64][129] (emit bank = (del+row)%32 -> 2-way = free).
//   2. per 2048-id chunk: filter (2 int4 loads/thread), compact matches
//      (atomicAdd on LDS counter, packed tok<<6|del), emit
//      tile[del][row] + b[row] with coalesced 256B/wave stores.
// W read exactly once, fully coalesced. Floor ~26us (131MB + 33MB @ 6.3TB/s).

#define VOCAB   32000
#define HIDDEN  1024
#define CBIN    64          // vocab columns per bin
#define NBIN    500         // 32000 / 64
#define ROWS    128         // h rows per block
#define RPAD    129         // transposed tile row stride (floats)
#define CHUNK   2048        // ids per filter pass
#define TMAX    2048        // worst-case matches per pass (== CHUNK, safe)

__global__ __launch_bounds__(256) void fused_onehot_kernel(
    const int* __restrict__ ids, int n,
    const float* __restrict__ W,
    const float* __restrict__ b,
    float* __restrict__ out)
{
    const int bin = blockIdx.x;        // 0..NBIN-1
    const int c0  = bin * CBIN;
    const int h0  = blockIdx.y * ROWS; // 0..HIDDEN-ROWS
    const int t   = threadIdx.x;

    __shared__ float tile[CBIN * RPAD];   // [del][row], padded
    __shared__ int   m_s[TMAX];           // packed (tok<<6)|del
    __shared__ int   cnt_s;

    // ---- stage W[h0:h0+ROWS, c0:c0+CBIN) -> LDS transposed ----
    // Loads: fully coalesced float4 (16 lanes x 64B = one row segment).
    const int c4 = (t & 15) * 4;          // column within bin
    const int r0 = t >> 4;                // base row (0..15)
    float4 wv[8];
    #pragma unroll
    for (int i = 0; i < 8; ++i) {
        const int r = r0 + 16 * i;
        wv[i] = *reinterpret_cast<const float4*>(
            &W[(size_t)(h0 + r) * VOCAB + c0 + c4]);
    }
    #pragma unroll
    for (int i = 0; i < 8; ++i) {
        const int r = r0 + 16 * i;
        tile[(c4 + 0) * RPAD + r] = wv[i].x;   // bank (c4+k+r)%32: 2-way, free
        tile[(c4 + 1) * RPAD + r] = wv[i].y;
        tile[(c4 + 2) * RPAD + r] = wv[i].z;
        tile[(c4 + 3) * RPAD + r] = wv[i].w;
    }

    const int   row  = t & (ROWS - 1);
    const float bias = b[h0 + row];
    const int   half = t >> 7;            // 2 tokens emitted in parallel

    // ---- filter -> compact -> emit, per 2048-id chunk ----
    for (int base = 0; base < n; base += CHUNK) {
        const int lim = min(n - base, CHUNK);

        __syncthreads();                  // tile staged / prev emit done
        if (t == 0) cnt_s = 0;
        __syncthreads();

        if (lim == CHUNK) {
            const int4* p = reinterpret_cast<const int4*>(ids + base) + t * 2;
            const int4 a = p[0], c = p[1];
            const int v[8] = {a.x, a.y, a.z, a.w, c.x, c.y, c.z, c.w};
            #pragma unroll
            for (int k = 0; k < 8; ++k) {
                const int d = v[k] - c0;
                if ((unsigned)d < CBIN) {
                    const int q = atomicAdd(&cnt_s, 1);
                    m_s[q] = ((base + t * 8 + k) << 6) | d;
                }
            }
        } else {
            for (int j = t; j < lim; j += 256) {
                const int d = ids[base + j] - c0;
                if ((unsigned)d < CBIN) {
                    const int q = atomicAdd(&cnt_s, 1);
                    m_s[q] = ((base + j) << 6) | d;
                }
            }
        }
        __syncthreads();

        const int cnt = cnt_s;
        for (int j = half; j < cnt; j += 2) {
            const int m   = m_s[j];
            const int tok = m >> 6;
            const int d   = m & (CBIN - 1);
            // 128 consecutive threads -> 512B contiguous store per token.
            out[(size_t)tok * HIDDEN + h0 + row] = tile[d * RPAD + row] + bias;
        }
    }
}

extern "C" void kernel_launch(void* const* d_in, const int* in_sizes, int n_in,
                              void* d_out, int out_size, void* d_ws, size_t ws_size,
                              hipStream_t stream)
{
    const int*   ids = (const int*)d_in[0];    // [BATCH*SEQ] int32
    const float* W   = (const float*)d_in[1];  // [HIDDEN, VOCAB] f32
    const float* b   = (const float*)d_in[2];  // [HIDDEN] f32
    float*       out = (float*)d_out;          // [BATCH*SEQ, HIDDEN] f32

    const int n_tokens = in_sizes[0];          // 8192

    fused_onehot_kernel<<<dim3(NBIN, HIDDEN / ROWS), dim3(256), 0, stream>>>(
        ids, n_tokens, W, b, out);
}

// Round 7
// 37.638 us; speedup vs baseline: 3.8598x; 1.1703x over previous
//
#include <hip/hip_runtime.h>

// out[token, h] = W[h, ids[token]] + b[h]   (one-hot matmul == column gather)
// W: [HIDDEN, VOCAB] row-major f32.
//
// Ladder: unsorted gather 170us (random-64B-line ceiling ~3.2TB/s) ->
// sorted gather 62.6us -> sort+stream 46.3us -> fused filter+stream 44.0us
// (CBIN=64: 256B read segments -> ~4.4TB/s effective).
// Round-7: CBIN=256 -> every W row segment is 1KB contiguous per wave
// instruction (the 6.3TB/s ubench pattern); ids preloaded to registers so
// the filter loop never touches L2; float4 emit stores (1KB/wave).
// W read exactly once, fully coalesced. Floor ~26us (131MB+33MB @ 6.3TB/s).

#define VOCAB   32000
#define HIDDEN  1024
#define CBIN    256          // vocab columns per bin (1KB rows)
#define NBIN    125          // 125*256 = 32000 exactly
#define ROWS    64           // h rows per block
#define NCH     (HIDDEN/ROWS)// 16 h-chunks
#define RPAD    260          // tile row stride (floats): 16B-aligned float4
#define CHUNK   2048         // ids per filter pass
#define NTOK    8192         // fast-path token count (B=4, S=2048)

__global__ __launch_bounds__(256) void fused_onehot_kernel(
    const int* __restrict__ ids, int n,
    const float* __restrict__ W,
    const float* __restrict__ b,
    float* __restrict__ out)
{
    const int bin = blockIdx.x;        // 0..NBIN-1
    const int c0  = bin * CBIN;
    const int h0  = blockIdx.y * ROWS; // 0..HIDDEN-ROWS
    const int t   = threadIdx.x;

    __shared__ float tile[ROWS * RPAD];   // [row][col], ~67KB
    __shared__ int   m_s[CHUNK];          // packed (tok<<8)|d
    __shared__ int   cnt_s[8];

    // ---- issue W loads: 1KB contiguous per wave instruction ----
    const int c4 = (t & 63) * 4;          // column within bin
    const int r0 = t >> 6;                // wave id -> base row
    float4 wv[16];
    #pragma unroll
    for (int i = 0; i < 16; ++i) {
        const int r = r0 + 4 * i;
        wv[i] = *reinterpret_cast<const float4*>(
            &W[(size_t)(h0 + r) * VOCAB + c0 + c4]);
    }

    // ---- preload ids into registers (issued while W loads in flight) ----
    int4 ida[4], idb[4];
    const bool fast = (n == NTOK);
    if (fast) {
        #pragma unroll
        for (int c = 0; c < 4; ++c) {
            const int4* p = reinterpret_cast<const int4*>(ids + c * CHUNK) + t * 2;
            ida[c] = p[0];
            idb[c] = p[1];
        }
    }

    if (t < 8) cnt_s[t] = 0;

    // ---- LDS stage (waits on W loads) ----
    #pragma unroll
    for (int i = 0; i < 16; ++i) {
        const int r = r0 + 4 * i;
        *reinterpret_cast<float4*>(&tile[r * RPAD + c4]) = wv[i];
    }

    const int g  = t & 15;                // thread within token-group
    const int q  = t >> 4;                // token-group (16 in parallel)
    const int r4 = g * 4;                 // 4 rows per thread
    const float4 bv = *reinterpret_cast<const float4*>(&b[h0 + r4]);

    if (fast) {
        #pragma unroll
        for (int c = 0; c < 4; ++c) {
            __syncthreads();              // tile ready (c=0) / m_s free (c>0)
            {
                const int4 a = ida[c], e = idb[c];
                const int v[8] = {a.x, a.y, a.z, a.w, e.x, e.y, e.z, e.w};
                const int tb = c * CHUNK + t * 8;
                #pragma unroll
                for (int k = 0; k < 8; ++k) {
                    const int d = v[k] - c0;
                    if ((unsigned)d < CBIN) {
                        const int p = atomicAdd(&cnt_s[c], 1);
                        m_s[p] = ((tb + k) << 8) | d;
                    }
                }
            }
            __syncthreads();
            const int cnt = cnt_s[c];
            for (int j = q; j < cnt; j += 16) {
                const int m   = m_s[j];
                const int tok = m >> 8;
                const int d   = m & 255;
                float4 o;
                o.x = tile[(r4 + 0) * RPAD + d] + bv.x;
                o.y = tile[(r4 + 1) * RPAD + d] + bv.y;
                o.z = tile[(r4 + 2) * RPAD + d] + bv.z;
                o.w = tile[(r4 + 3) * RPAD + d] + bv.w;
                // 16 lanes x 16B = 256B contiguous per token, 1KB per wave.
                *reinterpret_cast<float4*>(&out[(size_t)tok * HIDDEN + h0 + r4]) = o;
            }
        }
    } else {
        // Generic path (any n): in-loop scalar filter, 3 barriers/chunk.
        for (int base = 0; base < n; base += CHUNK) {
            const int lim = min(n - base, CHUNK);
            __syncthreads();              // prev emit done / tile ready
            if (t == 0) cnt_s[0] = 0;
            __syncthreads();
            for (int j = t; j < lim; j += 256) {
                const int d = ids[base + j] - c0;
                if ((unsigned)d < CBIN) {
                    const int p = atomicAdd(&cnt_s[0], 1);
                    m_s[p] = ((base + j) << 8) | d;
                }
            }
            __syncthreads();
            const int cnt = cnt_s[0];
            for (int j = q; j < cnt; j += 16) {
                const int m   = m_s[j];
                const int tok = m >> 8;
                const int d   = m & 255;
                float4 o;
                o.x = tile[(r4 + 0) * RPAD + d] + bv.x;
                o.y = tile[(r4 + 1) * RPAD + d] + bv.y;
                o.z = tile[(r4 + 2) * RPAD + d] + bv.z;
                o.w = tile[(r4 + 3) * RPAD + d] + bv.w;
                *reinterpret_cast<float4*>(&out[(size_t)tok * HIDDEN + h0 + r4]) = o;
            }
        }
    }
}

extern "C" void kernel_launch(void* const* d_in, const int* in_sizes, int n_in,
                              void* d_out, int out_size, void* d_ws, size_t ws_size,
                              hipStream_t stream)
{
    const int*   ids = (const int*)d_in[0];    // [BATCH*SEQ] int32
    const float* W   = (const float*)d_in[1];  // [HIDDEN, VOCAB] f32
    const float* b   = (const float*)d_in[2];  // [HIDDEN] f32
    float*       out = (float*)d_out;          // [BATCH*SEQ, HIDDEN] f32

    const int n_tokens = in_sizes[0];          // 8192

    fused_onehot_kernel<<<dim3(NBIN, NCH), dim3(256), 0, stream>>>(
        ids, n_tokens, W, b, out);
}